// Round 1
// baseline (408.089 us; speedup 1.0000x reference)
//
#include <hip/hip_runtime.h>

#define NXd 2048
#define NYd 2048

// ---------------------------------------------------------------------------
// Kernel 1: per-row flags  row_in[y] = any(lay[y,:]==1), row_out[y] = any(==3)
// ---------------------------------------------------------------------------
__global__ __launch_bounds__(256) void row_flags_kernel(const int* __restrict__ lay,
                                                        int* __restrict__ rin,
                                                        int* __restrict__ rout) {
    const int y = blockIdx.x;
    const int* row = lay + (size_t)y * NXd;
    int fin = 0, fout = 0;
    for (int x = threadIdx.x; x < NXd; x += 256) {
        const int L = row[x];
        fin  |= (L == 1);
        fout |= (L == 3);
    }
    __shared__ int s_in, s_out;
    if (threadIdx.x == 0) { s_in = 0; s_out = 0; }
    __syncthreads();
    const unsigned long long bi = __ballot(fin);
    const unsigned long long bo = __ballot(fout);
    if ((threadIdx.x & 63) == 0) {
        if (bi) atomicOr(&s_in, 1);
        if (bo) atomicOr(&s_out, 1);
    }
    __syncthreads();
    if (threadIdx.x == 0) { rin[y] = s_in; rout[y] = s_out; }
}

// ---------------------------------------------------------------------------
// Kernel 2: fused NSE residual + masks. One thread per full-grid pixel.
// ---------------------------------------------------------------------------
__global__ __launch_bounds__(256) void nse_main_kernel(const int* __restrict__ lay,
                                                       const float* __restrict__ flow,
                                                       const int* __restrict__ rin,
                                                       const int* __restrict__ rout,
                                                       float* __restrict__ out) {
    const int x = blockIdx.x * 256 + threadIdx.x;
    const int y = blockIdx.y;
    const size_t NN = (size_t)NXd * NYd;

    const float* __restrict__ f0 = flow;            // u
    const float* __restrict__ f1 = flow + NN;       // v
    const float* __restrict__ f2 = flow + 2 * NN;   // p

    const size_t idxC = (size_t)y * NXd + x;
    const int LC = lay[idxC];
    const int riny = rin[y];
    const int routy = rout[y];

    // ---- G_bc channels at (y,x) ----
    float gu = (LC == 2) ? 0.f : 1.f;
    float gv = gu, gp = gu;
    float valu = 0.f;
    if (x == 0 && riny)          { gu = 0.f; gv = 0.f; valu = 3.f; }
    if (x == NXd - 1 && routy)   { gp = 0.f; }
    const float g0   = (LC > 3) ? 0.f : 1.f;
    const float code = (LC > 3) ? (float)LC : 0.f;

    float* __restrict__ out_loss = out;                                   // (3,3,2046,2046)
    float* __restrict__ out_mask = out + (size_t)9 * 2046 * 2046;         // (1,3,2048,2048)
    float* __restrict__ out_gbcv = out_mask + 3 * NN;                     // (2,1,3,2048,2048)

    out_mask[0 * NN + idxC] = gu * g0 + code;
    out_mask[1 * NN + idxC] = gv * g0 + code;
    out_mask[2 * NN + idxC] = gp * g0 + code;
    out_gbcv[0 * NN + idxC] = gu;
    out_gbcv[1 * NN + idxC] = gv;
    out_gbcv[2 * NN + idxC] = gp;
    out_gbcv[3 * NN + idxC] = valu;
    out_gbcv[4 * NN + idxC] = 0.f;
    out_gbcv[5 * NN + idxC] = 0.f;

    if (x == 0 || x == NXd - 1 || y == 0 || y == NYd - 1) return;

    // ---- interior: 5-point stencil with BC masking ----
    const size_t iE = idxC + 1, iW = idxC - 1, iN = idxC - NXd, iS = idxC + NXd;
    const int LE = lay[iE], LW = lay[iW], LN = lay[iN], LS = lay[iS];

    const float uC = (LC == 2) ? 0.f : f0[idxC];
    const float uE = (LE == 2) ? 0.f : f0[iE];
    float       uW = (LW == 2) ? 0.f : f0[iW];
    const float uN = (LN == 2) ? 0.f : f0[iN];
    const float uS = (LS == 2) ? 0.f : f0[iS];

    const float vC = (LC == 2) ? 0.f : f1[idxC];
    const float vE = (LE == 2) ? 0.f : f1[iE];
    float       vW = (LW == 2) ? 0.f : f1[iW];
    const float vN = (LN == 2) ? 0.f : f1[iN];
    const float vS = (LS == 2) ? 0.f : f1[iS];

    if (x == 1 && riny) { uW = 3.f; vW = 0.f; }   // inflow BC at column 0

    const float pC = (LC == 2) ? 0.f : f2[idxC];
    float       pE = (LE == 2) ? 0.f : f2[iE];
    const float pW = (LW == 2) ? 0.f : f2[iW];
    const float pN = (LN == 2) ? 0.f : f2[iN];
    const float pS = (LS == 2) ? 0.f : f2[iS];

    if (x == NXd - 2 && routy) { pE = 0.f; }      // outflow BC at column NX-1

    const float dxu = 0.5f * (uE - uW);
    const float dyu = 0.5f * (uS - uN);           // Dy = 0.5*(a[y+1]-a[y-1])
    const float dxv = 0.5f * (vE - vW);
    const float dyv = 0.5f * (vS - vN);
    const float lapu = uN + uS + uW + uE - 4.f * uC;
    const float lapv = vN + vS + vW + vE - 4.f * vC;

    const float invh = (float)(2047.0 / 0.1);
    const float nuh2 = (float)(0.05 * (2047.0 / 0.1) * (2047.0 / 0.1));

    const int cs = (LC > 3) ? LC : 0;
    float dpx, dpy;
    if (cs == 4 || cs == 8 || cs == 11)       dpx = pE - pC;          // FDx
    else if (cs == 6 || cs == 9 || cs == 10)  dpx = pC - pW;          // BDx
    else                                      dpx = 0.5f * (pE - pW); // Dx
    if (cs == 7 || cs == 10 || cs == 11)      dpy = pN - pC;          // FDy = a[y-1]-a[y]
    else if (cs == 5 || cs == 8 || cs == 9)   dpy = pC - pS;          // BDy = a[y]-a[y+1]
    else                                      dpy = 0.5f * (pS - pN); // Dy

    const float zm = (LC == 2) ? 0.f : 1.f;
    const float mu   = zm * ((uC * dxu + vC * dyu + dpx) * invh - lapu * nuh2);
    const float mv   = zm * ((uC * dxv + vC * dyv + dpy) * invh - lapv * nuh2);
    const float cont = zm * ((dxu + dyv) * invh);

    const size_t PS = (size_t)2046 * 2046;
    const size_t li = (size_t)(y - 1) * 2046 + (x - 1);
    out_loss[0 * PS + li] = mu;
    out_loss[1 * PS + li] = mu;
    out_loss[2 * PS + li] = mu;
    out_loss[3 * PS + li] = mv;
    out_loss[4 * PS + li] = mv;
    out_loss[5 * PS + li] = mv;
    out_loss[6 * PS + li] = cont;
    out_loss[7 * PS + li] = cont;
    out_loss[8 * PS + li] = cont;
}

extern "C" void kernel_launch(void* const* d_in, const int* in_sizes, int n_in,
                              void* d_out, int out_size, void* d_ws, size_t ws_size,
                              hipStream_t stream) {
    const int*   layout = (const int*)d_in[0];
    const float* flow   = (const float*)d_in[1];
    const int*   lay    = layout + (size_t)NYd * NXd;   // layout[0,1] channel
    float* out = (float*)d_out;
    int* rin  = (int*)d_ws;
    int* rout = rin + NYd;

    row_flags_kernel<<<NYd, 256, 0, stream>>>(lay, rin, rout);

    dim3 grid(NXd / 256, NYd, 1);
    nse_main_kernel<<<grid, dim3(256, 1, 1), 0, stream>>>(lay, flow, rin, rout, out);
}